// Round 12
// baseline (601.751 us; speedup 1.0000x reference)
//
#include <hip/hip_runtime.h>
#include <hip/hip_cooperative_groups.h>
#include <limits.h>

namespace cg = cooperative_groups;

#define H 128

typedef __bf16 bf16x8 __attribute__((ext_vector_type(8)));
typedef __bf16 bf16x4 __attribute__((ext_vector_type(4)));
typedef float  f32x4  __attribute__((ext_vector_type(4)));

#define CUR_SENTINEL (INT_MIN / 2)

__device__ __forceinline__ int gate_to_gi(int g) {
    // GATE_CODES = (2, 3, 4, 1) -> gi 0..3
    switch (g) {
        case 2: return 0;
        case 3: return 1;
        case 4: return 2;
        case 1: return 3;
        default: return -1;
    }
}

struct Params {
    const int *gate, *ei, *lvl;
    const float *Ws_self, *Ws_nbr, *Wt_self, *Wt_nbr, *hs_W, *hs_b;
    const float *aW1, *ab1, *aW2, *ab2, *gWih, *gbih, *gbhh;
    int N, E, ECAP, NCAP, zn16;
    float *agg;
    int *cnt_in, *cnt_out, *ncnt, *galloc, *cursor;
    int2 *elist;
    int *nbuf;
    __bf16 *mir, *W1T, *W2T, *WihT, *hsWT;
    f32x4 *zbase;
    float *out;
};

struct SmemPrep  { float tile[32][33]; };
struct SmemAlloc { int lcnt[16]; int lbase[16]; };
struct SmemEnc   { __bf16 st[16][264]; };
struct SmemEdge  { __bf16 st[16][264]; __bf16 hid[16][136]; float msgbuf[16][132];
                   int ssrc[16]; int sdst[16]; int leadrow[17]; int nlead; };
struct SmemGru   { __bf16 x[16][136]; int nid[16]; };
union SmemAll { SmemPrep prep; SmemAlloc alloc; SmemEnc enc; SmemEdge edge; SmemGru gru; };

// ---------------- phase 0: zero cnt region + weight transposes (bf16, [out][k]) ----------------
__device__ void prep_phase(const Params& p, SmemPrep& sm) {
    const int tid = threadIdx.x;
    const int bid = blockIdx.x;
    const int nb = gridDim.x;
    f32x4 zero = {};
    for (int i = bid * 256 + tid; i < p.zn16; i += nb * 256) p.zbase[i] = zero;
    for (int id = bid; id < 416; id += nb) {
        const float* src; __bf16* dst; int K, C, t;
        if (id < 128)      { int z = id >> 5;           t = id & 31;        src = p.aW1 + (size_t)z * 256 * 128; dst = p.W1T + (size_t)z * 128 * 256; K = 256; C = 128; }
        else if (id < 192) { int z = (id - 128) >> 4;   t = (id - 128)&15;  src = p.aW2 + (size_t)z * 128 * 128; dst = p.W2T + (size_t)z * 128 * 128; K = 128; C = 128; }
        else if (id < 384) { int z = (id - 192) / 48;   t = (id - 192)%48;  src = p.gWih + (size_t)z * 128 * 384; dst = p.WihT + (size_t)z * 384 * 128; K = 128; C = 384; }
        else               { t = id - 384;              src = p.hs_W;       dst = p.hsWT; K = 256; C = 128; }
        const int tilesC = C >> 5;
        const int k0 = (t / tilesC) << 5;
        const int c0 = (t % tilesC) << 5;
        __syncthreads();
        #pragma unroll
        for (int e = 0; e < 4; ++e) {
            int pos = e * 256 + tid;
            int kk = pos >> 5, cc = pos & 31;
            sm.tile[kk][cc] = src[(size_t)(k0 + kk) * C + c0 + cc];
        }
        __syncthreads();
        #pragma unroll
        for (int e = 0; e < 4; ++e) {
            int pos = e * 256 + tid;
            int cc = pos >> 5, kk = pos & 31;
            dst[(size_t)(c0 + cc) * K + k0 + kk] = (__bf16)sm.tile[kk][cc];
        }
    }
}

// ---------------- phase 1: degree histograms ----------------
__device__ void hist_phase(const Params& p) {
    for (int e = blockIdx.x * 256 + threadIdx.x; e < p.E; e += gridDim.x * 256) {
        int s = p.ei[e], d = p.ei[p.E + e];
        atomicAdd(&p.cnt_in[d * 6 + p.gate[s]], 1);
        atomicAdd(&p.cnt_out[s * 6 + p.gate[d]], 1);
    }
}

// ---------------- phase 2: node bucketing + edge-segment allocation ----------------
__device__ void alloc_phase(const Params& p, SmemAlloc& sm) {
    const int tid = threadIdx.x;
    for (int base = blockIdx.x * 256; base < p.N; base += gridDim.x * 256) {
        if (tid < 16) sm.lcnt[tid] = 0;
        __syncthreads();
        int n = base + tid;
        int b = -1, local = 0, nlocal = 0;
        if (n < p.N) {
            int gi = gate_to_gi(p.gate[n]);
            int L = p.lvl[n];
            if (gi >= 0 && L >= 1 && L <= 2) {
                b = (L - 1) * 4 + gi;
                int deg = 0;
                #pragma unroll
                for (int c = 0; c < 6; ++c) deg += p.cnt_in[n * 6 + c];
                local = atomicAdd(&sm.lcnt[b], deg);
                nlocal = atomicAdd(&sm.lcnt[8 + b], 1);
            }
        }
        __syncthreads();
        if (tid < 8)       sm.lbase[tid] = atomicAdd(&p.galloc[tid], sm.lcnt[tid]);
        else if (tid < 16) sm.lbase[tid] = atomicAdd(&p.ncnt[tid - 8], sm.lcnt[tid]);
        __syncthreads();
        if (n < p.N) {
            if (b >= 0) {
                p.cursor[n] = b * p.ECAP + sm.lbase[b] + local;
                int q = sm.lbase[8 + b] + nlocal;
                if (q < p.NCAP) p.nbuf[b * p.NCAP + q] = n;
            } else {
                p.cursor[n] = CUR_SENTINEL;
            }
        }
        __syncthreads();
    }
}

// ---------------- phase 3: scatter (src,dst) into dst-contiguous lists ----------------
__device__ void scatter_phase(const Params& p) {
    for (int e = blockIdx.x * 256 + threadIdx.x; e < p.E; e += gridDim.x * 256) {
        int d = p.ei[p.E + e];
        int slot = atomicAdd(&p.cursor[d], 1);
        if (slot >= 0) p.elist[slot] = make_int2(p.ei[e], d);
    }
}

// ---------------- phase 4: encoder ----------------
__device__ void encoder_phase(const Params& p, SmemEnc& sm) {
    const int tid = threadIdx.x;
    const int lane = tid & 63;
    const int w = tid >> 6;
    const int row = tid >> 4;
    const int c0 = (tid & 15) * 8;
    const int N = p.N;

    bf16x8 bw[8][2];
    #pragma unroll
    for (int kk = 0; kk < 8; ++kk)
        #pragma unroll
        for (int j = 0; j < 2; ++j) {
            int col = w * 32 + j * 16 + (lane & 15);
            bw[kk][j] = *(const bf16x8*)&p.hsWT[(size_t)col * 256 + kk * 32 + (lane >> 4) * 8];
        }
    float hbc[2];
    #pragma unroll
    for (int j = 0; j < 2; ++j) hbc[j] = p.hs_b[w * 32 + j * 16 + (lane & 15)];

    const int ntiles = (N + 15) >> 4;
    for (int t = blockIdx.x; t < ntiles; t += gridDim.x) {
        const int base = t * 16;
        int n = base + row;
        if (n >= N) n = N - 1;
        const int g = p.gate[n];
        const int L = p.lvl[n];
        int cin[6], cout[6];
        #pragma unroll
        for (int k = 0; k < 6; ++k) { cin[k] = p.cnt_in[n * 6 + k]; cout[k] = p.cnt_out[n * 6 + k]; }
        f32x4 s0 = *(const f32x4*)&p.Ws_self[g * H + c0];
        f32x4 s1 = *(const f32x4*)&p.Ws_self[g * H + c0 + 4];
        f32x4 t0 = *(const f32x4*)&p.Wt_self[g * H + c0];
        f32x4 t1 = *(const f32x4*)&p.Wt_self[g * H + c0 + 4];
        #pragma unroll
        for (int k = 0; k < 6; ++k) {
            float ci = (float)cin[k], co = (float)cout[k];
            s0 += ci * *(const f32x4*)&p.Ws_nbr[k * H + c0];
            s1 += ci * *(const f32x4*)&p.Ws_nbr[k * H + c0 + 4];
            t0 += co * *(const f32x4*)&p.Wt_nbr[k * H + c0];
            t1 += co * *(const f32x4*)&p.Wt_nbr[k * H + c0 + 4];
        }
        bf16x8 ps, pt;
        #pragma unroll
        for (int j = 0; j < 4; ++j) {
            ps[j]     = (__bf16)fmaxf(s0[j], 0.f);
            ps[4 + j] = (__bf16)fmaxf(s1[j], 0.f);
            pt[j]     = (__bf16)fmaxf(t0[j], 0.f);
            pt[4 + j] = (__bf16)fmaxf(t1[j], 0.f);
        }
        *(bf16x8*)&sm.st[row][c0]       = ps;
        *(bf16x8*)&sm.st[row][128 + c0] = pt;
        if (base + row < N) {
            f32x4 z = {};
            bf16x8 zb = {};
            *(bf16x8*)&p.mir[(size_t)n * 256 + 128 + c0] = zb;
            const bool bucketed = (gate_to_gi(g) >= 0 && L >= 1 && L <= 2);
            if (bucketed) {
                *(f32x4*)&p.agg[(size_t)n * H + c0]     = z;
                *(f32x4*)&p.agg[(size_t)n * H + c0 + 4] = z;
            } else {
                *(f32x4*)&p.out[(size_t)N * H + (size_t)n * H + c0]     = z;
                *(f32x4*)&p.out[(size_t)N * H + (size_t)n * H + c0 + 4] = z;
            }
        }
        __syncthreads();
        f32x4 acc[2] = {};
        #pragma unroll
        for (int kk = 0; kk < 8; ++kk) {
            bf16x8 a = *(const bf16x8*)&sm.st[lane & 15][kk * 32 + (lane >> 4) * 8];
            #pragma unroll
            for (int j = 0; j < 2; ++j)
                acc[j] = __builtin_amdgcn_mfma_f32_16x16x32_bf16(a, bw[kk][j], acc[j], 0, 0, 0);
        }
        #pragma unroll
        for (int j = 0; j < 2; ++j) {
            int col = w * 32 + j * 16 + (lane & 15);
            #pragma unroll
            for (int r = 0; r < 4; ++r) {
                int nn = base + (lane >> 4) * 4 + r;
                if (nn < N) {
                    float v = acc[j][r] + hbc[j];
                    p.out[(size_t)nn * H + col] = v;
                    p.mir[(size_t)nn * 256 + col] = (__bf16)v;
                }
            }
        }
        __syncthreads();
    }
}

// ---------------- phase 5/7: edge messages (gi = blockIdx&3) ----------------
template<int KHALF>
__device__ void edge_phase(const Params& p, SmemEdge& sm, int level) {
    const int tid = threadIdx.x;
    const int bid = blockIdx.x;
    const int gi = bid & 3;
    const int xb = bid >> 2;
    const int xstep = gridDim.x >> 2;
    const int b = (level - 1) * 4 + gi;
    const int ecnt = p.galloc[b];
    const int ntiles = (ecnt + 15) >> 4;
    if (ntiles == 0) return;

    const int lane = tid & 63;
    const int w = tid >> 6;
    const __bf16* w1 = p.W1T + (size_t)gi * 128 * 256;
    const __bf16* w2 = p.W2T + (size_t)gi * 128 * 128;

    bf16x8 w1f[KHALF][2], w2f[4][2];
    #pragma unroll
    for (int kk = 0; kk < KHALF; ++kk)
        #pragma unroll
        for (int j = 0; j < 2; ++j) {
            int col = w * 32 + j * 16 + (lane & 15);
            w1f[kk][j] = *(const bf16x8*)&w1[(size_t)col * 256 + kk * 32 + (lane >> 4) * 8];
        }
    #pragma unroll
    for (int kk = 0; kk < 4; ++kk)
        #pragma unroll
        for (int j = 0; j < 2; ++j) {
            int col = w * 32 + j * 16 + (lane & 15);
            w2f[kk][j] = *(const bf16x8*)&w2[(size_t)col * 128 + kk * 32 + (lane >> 4) * 8];
        }
    float b1c[2], b2c[2];
    #pragma unroll
    for (int j = 0; j < 2; ++j) {
        int col = w * 32 + j * 16 + (lane & 15);
        b1c[j] = p.ab1[gi * H + col];
        b2c[j] = p.ab2[gi * H + col];
    }

    for (int t = xb; t < ntiles; t += xstep) {
        const int base = t * 16;
        const int rem = min(16, ecnt - base);
        if (tid < 64) {
            if (tid < 16) {
                int2 e = p.elist[b * p.ECAP + base + min(tid, rem - 1)];
                sm.ssrc[tid] = e.x;
                sm.sdst[tid] = e.y;
            }
            bool flag = (tid < rem) && (tid == 0 || sm.sdst[tid] != sm.sdst[tid - 1]);
            unsigned long long m = __ballot(flag);
            if (flag) {
                int rank = __popcll(m & ((1ull << tid) - 1));
                sm.leadrow[rank] = tid;
            }
            if (tid == 0) {
                int nl = __popcll(m);
                sm.nlead = nl;
                sm.leadrow[nl] = rem;
            }
        }
        __syncthreads();
        #pragma unroll
        for (int rep = 0; rep < KHALF / 4; ++rep) {
            int idx = rep * 256 + tid;
            int r = idx / (KHALF * 4);
            int c = idx - r * (KHALF * 4);
            *(bf16x8*)&sm.st[r][c * 8] = *(const bf16x8*)&p.mir[(size_t)sm.ssrc[r] * 256 + c * 8];
        }
        __syncthreads();
        f32x4 acc[2] = {};
        #pragma unroll
        for (int kk = 0; kk < KHALF; ++kk) {
            bf16x8 a = *(const bf16x8*)&sm.st[lane & 15][kk * 32 + (lane >> 4) * 8];
            #pragma unroll
            for (int j = 0; j < 2; ++j)
                acc[j] = __builtin_amdgcn_mfma_f32_16x16x32_bf16(a, w1f[kk][j], acc[j], 0, 0, 0);
        }
        #pragma unroll
        for (int j = 0; j < 2; ++j) {
            int col = w * 32 + j * 16 + (lane & 15);
            #pragma unroll
            for (int r = 0; r < 4; ++r)
                sm.hid[(lane >> 4) * 4 + r][col] = (__bf16)fmaxf(acc[j][r] + b1c[j], 0.f);
        }
        __syncthreads();
        f32x4 acc2[2] = {};
        #pragma unroll
        for (int kk = 0; kk < 4; ++kk) {
            bf16x8 a = *(const bf16x8*)&sm.hid[lane & 15][kk * 32 + (lane >> 4) * 8];
            #pragma unroll
            for (int j = 0; j < 2; ++j)
                acc2[j] = __builtin_amdgcn_mfma_f32_16x16x32_bf16(a, w2f[kk][j], acc2[j], 0, 0, 0);
        }
        #pragma unroll
        for (int j = 0; j < 2; ++j) {
            int col = w * 32 + j * 16 + (lane & 15);
            #pragma unroll
            for (int r = 0; r < 4; ++r)
                sm.msgbuf[(lane >> 4) * 4 + r][col] = acc2[j][r] + b2c[j];
        }
        __syncthreads();
        const int nl = sm.nlead;
        for (int idx = tid; idx < (nl << 7); idx += 256) {
            int li = idx >> 7, c = idx & 127;
            int r0 = sm.leadrow[li], r1 = sm.leadrow[li + 1];
            float s = sm.msgbuf[r0][c];
            for (int r = r0 + 1; r < r1; ++r) s += sm.msgbuf[r][c];
            atomicAdd(&p.agg[(size_t)sm.sdst[r0] * H + c], s);
        }
        __syncthreads();
    }
}

// ---------------- phase 6/8: GRU ----------------
__device__ void gru_phase(const Params& p, SmemGru& sm, int level) {
    const int tid = threadIdx.x;
    const int bid = blockIdx.x;
    const int gi = bid & 3;
    const int xb = bid >> 2;
    const int xstep = gridDim.x >> 2;
    const int bucket = (level - 1) * 4 + gi;
    const int cnt = min(p.ncnt[bucket], p.NCAP);
    const int ntiles = (cnt + 15) >> 4;
    if (ntiles == 0) return;

    const int lane = tid & 63;
    const int w = tid >> 6;
    const int N = p.N;
    const __bf16* wih = p.WihT + (size_t)gi * 384 * 128;

    bf16x8 wf[4][3][2];
    #pragma unroll
    for (int kk = 0; kk < 4; ++kk)
        #pragma unroll
        for (int q = 0; q < 3; ++q)
            #pragma unroll
            for (int j = 0; j < 2; ++j) {
                int oc = q * 128 + w * 32 + j * 16 + (lane & 15);
                wf[kk][q][j] = *(const bf16x8*)&wih[(size_t)oc * 128 + kk * 32 + (lane >> 4) * 8];
            }
    float bir[2], biz[2], bin[2], bhn[2];
    #pragma unroll
    for (int j = 0; j < 2; ++j) {
        int col = w * 32 + j * 16 + (lane & 15);
        bir[j] = p.gbih[gi * 384 + col] + p.gbhh[gi * 384 + col];
        biz[j] = p.gbih[gi * 384 + 128 + col] + p.gbhh[gi * 384 + 128 + col];
        bin[j] = p.gbih[gi * 384 + 256 + col];
        bhn[j] = p.gbhh[gi * 384 + 256 + col];
    }

    for (int t = xb; t < ntiles; t += xstep) {
        const int base = t * 16;
        const int rem = min(16, cnt - base);
        if (tid < 16) sm.nid[tid] = p.nbuf[bucket * p.NCAP + base + min(tid, rem - 1)];
        __syncthreads();
        #pragma unroll
        for (int rep = 0; rep < 2; ++rep) {
            int idx = rep * 256 + tid;
            int row = idx >> 5, c4 = idx & 31;
            f32x4 v = *(const f32x4*)&p.agg[(size_t)sm.nid[row] * H + c4 * 4];
            bf16x4 pk;
            pk[0] = (__bf16)v[0]; pk[1] = (__bf16)v[1]; pk[2] = (__bf16)v[2]; pk[3] = (__bf16)v[3];
            *(bf16x4*)&sm.x[row][c4 * 4] = pk;
        }
        __syncthreads();
        f32x4 acc[3][2] = {};
        #pragma unroll
        for (int kk = 0; kk < 4; ++kk) {
            bf16x8 a = *(const bf16x8*)&sm.x[lane & 15][kk * 32 + (lane >> 4) * 8];
            #pragma unroll
            for (int q = 0; q < 3; ++q)
                #pragma unroll
                for (int j = 0; j < 2; ++j)
                    acc[q][j] = __builtin_amdgcn_mfma_f32_16x16x32_bf16(a, wf[kk][q][j], acc[q][j], 0, 0, 0);
        }
        #pragma unroll
        for (int j = 0; j < 2; ++j) {
            int col = w * 32 + j * 16 + (lane & 15);
            #pragma unroll
            for (int r = 0; r < 4; ++r) {
                int row = (lane >> 4) * 4 + r;
                if (row >= rem) continue;
                float rr = 1.f / (1.f + expf(-(acc[0][j][r] + bir[j])));
                float zz = 1.f / (1.f + expf(-(acc[1][j][r] + biz[j])));
                float nn = tanhf(acc[2][j][r] + bin[j] + rr * bhn[j]);
                float h = (1.f - zz) * nn;
                p.out[(size_t)N * H + (size_t)sm.nid[row] * H + col] = h;
                p.mir[(size_t)sm.nid[row] * 256 + 128 + col] = (__bf16)h;
            }
        }
        __syncthreads();
    }
}

// ---------------- fused cooperative kernel ----------------
__global__ __launch_bounds__(256, 2)
void fused_all(Params p) {
    cg::grid_group grid = cg::this_grid();
    __shared__ SmemAll sm;

    prep_phase(p, sm.prep);
    __threadfence(); grid.sync();
    hist_phase(p);
    __threadfence(); grid.sync();
    alloc_phase(p, sm.alloc);
    __threadfence(); grid.sync();
    scatter_phase(p);
    __threadfence(); grid.sync();
    encoder_phase(p, sm.enc);
    __threadfence(); grid.sync();
    edge_phase<4>(p, sm.edge, 1);
    __threadfence(); grid.sync();
    gru_phase(p, sm.gru, 1);
    __threadfence(); grid.sync();
    edge_phase<8>(p, sm.edge, 2);
    __threadfence(); grid.sync();
    gru_phase(p, sm.gru, 2);
}

// ---------------- fallback: multi-kernel wrappers (round-10 pipeline) ----------------
__global__ __launch_bounds__(256) void k_prep(Params p)    { __shared__ SmemPrep sm;  prep_phase(p, sm); }
__global__ __launch_bounds__(256) void k_hist(Params p)    { hist_phase(p); }
__global__ __launch_bounds__(256) void k_alloc(Params p)   { __shared__ SmemAlloc sm; alloc_phase(p, sm); }
__global__ __launch_bounds__(256) void k_scatter(Params p) { scatter_phase(p); }
__global__ __launch_bounds__(256, 2) void k_enc(Params p)  { __shared__ SmemEnc sm;   encoder_phase(p, sm); }
template<int KH>
__global__ __launch_bounds__(256, 2) void k_edge(Params p, int level) { __shared__ SmemEdge sm; edge_phase<KH>(p, sm, level); }
__global__ __launch_bounds__(256, 2) void k_gru(Params p, int level)  { __shared__ SmemGru sm;  gru_phase(p, sm, level); }

extern "C" void kernel_launch(void* const* d_in, const int* in_sizes, int n_in,
                              void* d_out, int out_size, void* d_ws, size_t ws_size,
                              hipStream_t stream) {
    const int N = in_sizes[0];
    const int E = in_sizes[1] / 2;
    const int ECAP = ((E / 4) + 15) & ~15;
    const int NCAP = ((N / 4) + 15) & ~15;

    char* wsb = (char*)d_ws;
    size_t off = 0;
    float* agg = (float*)(wsb + off);         off += (size_t)N * H * sizeof(float);
    const size_t zstart = off;
    int* cnt_in = (int*)(wsb + off);          off += (size_t)N * 6 * sizeof(int);
    int* cnt_out = (int*)(wsb + off);         off += (size_t)N * 6 * sizeof(int);
    int* ncnt = (int*)(wsb + off);            off += 8 * sizeof(int);
    int* galloc = (int*)(wsb + off);          off += 8 * sizeof(int); off = (off + 63) & ~(size_t)63;
    const size_t zero_bytes = off - zstart;
    int* cursor = (int*)(wsb + off);          off += (size_t)N * sizeof(int); off = (off + 7) & ~(size_t)7;
    int2* elist = (int2*)(wsb + off);         off += (size_t)8 * ECAP * sizeof(int2);
    int* nbuf   = (int*)(wsb + off);          off += (size_t)8 * NCAP * sizeof(int);
    __bf16* mir = (__bf16*)(wsb + off);       off += (size_t)N * 256 * sizeof(__bf16);
    __bf16* W1T = (__bf16*)(wsb + off);       off += (size_t)4 * 128 * 256 * 2;
    __bf16* W2T = (__bf16*)(wsb + off);       off += (size_t)4 * 128 * 128 * 2;
    __bf16* WihT = (__bf16*)(wsb + off);      off += (size_t)4 * 384 * 128 * 2;
    __bf16* hsWT = (__bf16*)(wsb + off);      off += (size_t)128 * 256 * 2;

    Params prm;
    prm.gate    = (const int*)d_in[0];
    prm.ei      = (const int*)d_in[1];
    prm.lvl     = (const int*)d_in[2];
    prm.Ws_self = (const float*)d_in[4];
    prm.Ws_nbr  = (const float*)d_in[5];
    prm.Wt_self = (const float*)d_in[6];
    prm.Wt_nbr  = (const float*)d_in[7];
    prm.hs_W    = (const float*)d_in[8];
    prm.hs_b    = (const float*)d_in[9];
    prm.aW1     = (const float*)d_in[10];
    prm.ab1     = (const float*)d_in[11];
    prm.aW2     = (const float*)d_in[12];
    prm.ab2     = (const float*)d_in[13];
    prm.gWih    = (const float*)d_in[14];
    prm.gbih    = (const float*)d_in[15];
    // d_in[16] = gru_Whh unused (h == 0 at each node's single update)
    prm.gbhh    = (const float*)d_in[17];
    prm.N = N; prm.E = E; prm.ECAP = ECAP; prm.NCAP = NCAP;
    prm.zn16 = (int)(zero_bytes / 16);
    prm.agg = agg; prm.cnt_in = cnt_in; prm.cnt_out = cnt_out;
    prm.ncnt = ncnt; prm.galloc = galloc; prm.cursor = cursor;
    prm.elist = elist; prm.nbuf = nbuf;
    prm.mir = mir; prm.W1T = W1T; prm.W2T = W2T; prm.WihT = WihT; prm.hsWT = hsWT;
    prm.zbase = (f32x4*)(wsb + zstart);
    prm.out = (float*)d_out;

    // ---- adaptive cooperative launch with checked fallback ----
    hipError_t lerr = hipErrorUnknown;
    int bpc = 0;
    hipError_t qerr = hipOccupancyMaxActiveBlocksPerMultiprocessor(&bpc, fused_all, 256, 0);
    if (qerr == hipSuccess && bpc > 0) {
        int grid = bpc * 256;               // 256 CUs on MI355X
        if (grid > 512) grid = 512;
        grid &= ~3;                         // edge/gru phases need gridDim.x % 4 == 0
        if (grid >= 8) {
            void* kargs[] = { &prm };
            lerr = hipLaunchCooperativeKernel((void*)fused_all, dim3(grid), dim3(256), kargs, 0, stream);
        }
    }
    if (lerr != hipSuccess) {
        // round-10 multi-kernel pipeline (known-good, ~131us)
        k_prep<<<416, 256, 0, stream>>>(prm);
        k_hist<<<(E + 255) / 256, 256, 0, stream>>>(prm);
        k_alloc<<<(N + 255) / 256, 256, 0, stream>>>(prm);
        k_scatter<<<(E + 255) / 256, 256, 0, stream>>>(prm);
        k_enc<<<512, 256, 0, stream>>>(prm);
        k_edge<4><<<512, 256, 0, stream>>>(prm, 1);
        k_gru<<<512, 256, 0, stream>>>(prm, 1);
        k_edge<8><<<512, 256, 0, stream>>>(prm, 2);
        k_gru<<<512, 256, 0, stream>>>(prm, 2);
    }
}

// Round 13
// 129.833 us; speedup vs baseline: 4.6348x; 4.6348x over previous
//
#include <hip/hip_runtime.h>
#include <limits.h>

#define H 128

typedef __bf16 bf16x8 __attribute__((ext_vector_type(8)));
typedef __bf16 bf16x4 __attribute__((ext_vector_type(4)));
typedef float  f32x4  __attribute__((ext_vector_type(4)));

#define CUR_SENTINEL (INT_MIN / 2)

__device__ __forceinline__ int gate_to_gi(int g) {
    // GATE_CODES = (2, 3, 4, 1) -> gi 0..3
    switch (g) {
        case 2: return 0;
        case 3: return 1;
        case 4: return 2;
        case 1: return 3;
        default: return -1;
    }
}

// ---------------- weight prep (tiled transpose + bf16) fused with ws zeroing ----------------
__global__ __launch_bounds__(256)
void prep_weights(const float* __restrict__ aW1, const float* __restrict__ aW2,
                  const float* __restrict__ gWih, const float* __restrict__ hsW,
                  __bf16* __restrict__ W1T, __bf16* __restrict__ W2T,
                  __bf16* __restrict__ WihT, __bf16* __restrict__ hsWT,
                  f32x4* __restrict__ zbase, int zn16) {
    const int z = blockIdx.z;
    const int tid = threadIdx.x;
    if (z == 14) {   // zero plane: cnt_in/cnt_out/ncnt/galloc
        f32x4 zero = {};
        for (int i = blockIdx.x * 256 + tid; i < zn16; i += gridDim.x * 256) zbase[i] = zero;
        return;
    }
    const float* src;
    __bf16* dst;
    int K, C;
    if (z < 4)       { src = aW1 + (size_t)z * 256 * 128;       dst = W1T + (size_t)z * 128 * 256; K = 256; C = 128; }
    else if (z < 8)  { src = aW2 + (size_t)(z - 4) * 128 * 128; dst = W2T + (size_t)(z - 4) * 128 * 128; K = 128; C = 128; }
    else if (z < 12) { src = gWih + (size_t)(z - 8) * 128 * 384; dst = WihT + (size_t)(z - 8) * 384 * 128; K = 128; C = 384; }
    else             { src = hsW;                                dst = hsWT;                        K = 256; C = 128; }
    __shared__ float tile[32][33];
    const int tilesC = C >> 5;
    const int ntile = (K >> 5) * tilesC;
    const int t = blockIdx.x;
    if (t >= ntile) return;
    const int k0 = (t / tilesC) << 5;
    const int c0 = (t % tilesC) << 5;
    #pragma unroll
    for (int e = 0; e < 4; ++e) {
        int pos = e * 256 + tid;
        int kk = pos >> 5, cc = pos & 31;
        tile[kk][cc] = src[(size_t)(k0 + kk) * C + c0 + cc];
    }
    __syncthreads();
    #pragma unroll
    for (int e = 0; e < 4; ++e) {
        int pos = e * 256 + tid;
        int cc = pos >> 5, kk = pos & 31;
        dst[(size_t)(c0 + cc) * K + k0 + kk] = (__bf16)tile[kk][cc];
    }
}

// ---------------- degree histograms (pure edge pass) ----------------
__global__ __launch_bounds__(256)
void hist_kernel(const int* __restrict__ gate, const int* __restrict__ ei, int E,
                 int* __restrict__ cnt_in, int* __restrict__ cnt_out) {
    int e = blockIdx.x * blockDim.x + threadIdx.x;
    if (e >= E) return;
    int s = ei[e], d = ei[E + e];
    atomicAdd(&cnt_in[d * 6 + gate[s]], 1);
    atomicAdd(&cnt_out[s * 6 + gate[d]], 1);
}

// ---------------- fused: node alloc (blocks < AB) || encoder (blocks >= AB) ----------------
// Both depend only on hist; disjoint outputs. One launch+drain saved, alloc latency hidden.
__global__ __launch_bounds__(256, 2)
void alloc_enc(const int* __restrict__ gate, const int* __restrict__ lvl,
               const int* __restrict__ cnt_in, const int* __restrict__ cnt_out,
               int N, int ECAP, int NCAP,
               int* __restrict__ galloc, int* __restrict__ ncnt,
               int* __restrict__ cursor, int* __restrict__ nbuf,
               const float* __restrict__ Ws_self, const float* __restrict__ Ws_nbr,
               const float* __restrict__ Wt_self, const float* __restrict__ Wt_nbr,
               const __bf16* __restrict__ hsWT, const float* __restrict__ hs_b,
               float* __restrict__ out, __bf16* __restrict__ mir,
               float* __restrict__ agg, int AB) {
    struct SA { int lcnt[16]; int lbase[16]; };
    struct SE { __bf16 st[16][264]; };
    __shared__ union { SA a; SE e; } sm;
    const int tid = threadIdx.x;

    if ((int)blockIdx.x < AB) {
        // ---- alloc role ----
        for (int base = blockIdx.x * 256; base < N; base += AB * 256) {
            if (tid < 16) sm.a.lcnt[tid] = 0;
            __syncthreads();
            int n = base + tid;
            int b = -1, local = 0, nlocal = 0;
            if (n < N) {
                int gi = gate_to_gi(gate[n]);
                int L = lvl[n];
                if (gi >= 0 && L >= 1 && L <= 2) {
                    b = (L - 1) * 4 + gi;
                    int deg = 0;
                    #pragma unroll
                    for (int c = 0; c < 6; ++c) deg += cnt_in[n * 6 + c];
                    local = atomicAdd(&sm.a.lcnt[b], deg);
                    nlocal = atomicAdd(&sm.a.lcnt[8 + b], 1);
                }
            }
            __syncthreads();
            if (tid < 8)       sm.a.lbase[tid] = atomicAdd(&galloc[tid], sm.a.lcnt[tid]);
            else if (tid < 16) sm.a.lbase[tid] = atomicAdd(&ncnt[tid - 8], sm.a.lcnt[tid]);
            __syncthreads();
            if (n < N) {
                if (b >= 0) {
                    cursor[n] = b * ECAP + sm.a.lbase[b] + local;
                    int q = sm.a.lbase[8 + b] + nlocal;
                    if (q < NCAP) nbuf[b * NCAP + q] = n;
                } else {
                    cursor[n] = CUR_SENTINEL;
                }
            }
            __syncthreads();
        }
        return;
    }

    // ---- encoder role ----
    const int xb = blockIdx.x - AB;
    const int xstep = gridDim.x - AB;
    const int lane = tid & 63;
    const int w = tid >> 6;
    const int row = tid >> 4;
    const int c0 = (tid & 15) * 8;

    bf16x8 bw[8][2];
    #pragma unroll
    for (int kk = 0; kk < 8; ++kk)
        #pragma unroll
        for (int j = 0; j < 2; ++j) {
            int col = w * 32 + j * 16 + (lane & 15);
            bw[kk][j] = *(const bf16x8*)&hsWT[(size_t)col * 256 + kk * 32 + (lane >> 4) * 8];
        }
    float hbc[2];
    #pragma unroll
    for (int j = 0; j < 2; ++j) hbc[j] = hs_b[w * 32 + j * 16 + (lane & 15)];

    const int ntiles = (N + 15) >> 4;
    for (int t = xb; t < ntiles; t += xstep) {
        const int base = t * 16;
        int n = base + row;
        if (n >= N) n = N - 1;
        const int g = gate[n];
        const int L = lvl[n];
        int cin[6], cout[6];
        #pragma unroll
        for (int k = 0; k < 6; ++k) { cin[k] = cnt_in[n * 6 + k]; cout[k] = cnt_out[n * 6 + k]; }
        f32x4 s0 = *(const f32x4*)&Ws_self[g * H + c0];
        f32x4 s1 = *(const f32x4*)&Ws_self[g * H + c0 + 4];
        f32x4 t0 = *(const f32x4*)&Wt_self[g * H + c0];
        f32x4 t1 = *(const f32x4*)&Wt_self[g * H + c0 + 4];
        #pragma unroll
        for (int k = 0; k < 6; ++k) {
            float ci = (float)cin[k], co = (float)cout[k];
            s0 += ci * *(const f32x4*)&Ws_nbr[k * H + c0];
            s1 += ci * *(const f32x4*)&Ws_nbr[k * H + c0 + 4];
            t0 += co * *(const f32x4*)&Wt_nbr[k * H + c0];
            t1 += co * *(const f32x4*)&Wt_nbr[k * H + c0 + 4];
        }
        bf16x8 ps, pt;
        #pragma unroll
        for (int j = 0; j < 4; ++j) {
            ps[j]     = (__bf16)fmaxf(s0[j], 0.f);
            ps[4 + j] = (__bf16)fmaxf(s1[j], 0.f);
            pt[j]     = (__bf16)fmaxf(t0[j], 0.f);
            pt[4 + j] = (__bf16)fmaxf(t1[j], 0.f);
        }
        *(bf16x8*)&sm.e.st[row][c0]       = ps;
        *(bf16x8*)&sm.e.st[row][128 + c0] = pt;
        if (base + row < N) {
            f32x4 z = {};
            bf16x8 zb = {};
            *(bf16x8*)&mir[(size_t)n * 256 + 128 + c0] = zb;   // mir hf = 0
            const bool bucketed = (gate_to_gi(g) >= 0 && L >= 1 && L <= 2);
            if (bucketed) {
                *(f32x4*)&agg[(size_t)n * H + c0]     = z;
                *(f32x4*)&agg[(size_t)n * H + c0 + 4] = z;
            } else {
                *(f32x4*)&out[(size_t)N * H + (size_t)n * H + c0]     = z;
                *(f32x4*)&out[(size_t)N * H + (size_t)n * H + c0 + 4] = z;
            }
        }
        __syncthreads();
        f32x4 acc[2] = {};
        #pragma unroll
        for (int kk = 0; kk < 8; ++kk) {
            bf16x8 a = *(const bf16x8*)&sm.e.st[lane & 15][kk * 32 + (lane >> 4) * 8];
            #pragma unroll
            for (int j = 0; j < 2; ++j)
                acc[j] = __builtin_amdgcn_mfma_f32_16x16x32_bf16(a, bw[kk][j], acc[j], 0, 0, 0);
        }
        #pragma unroll
        for (int j = 0; j < 2; ++j) {
            int col = w * 32 + j * 16 + (lane & 15);
            #pragma unroll
            for (int r = 0; r < 4; ++r) {
                int nn = base + (lane >> 4) * 4 + r;
                if (nn < N) {
                    float v = acc[j][r] + hbc[j];
                    out[(size_t)nn * H + col] = v;
                    mir[(size_t)nn * 256 + col] = (__bf16)v;
                }
            }
        }
        __syncthreads();
    }
}

// ---------------- scatter (src,dst) into per-node (dst-contiguous) edge lists ----------------
__global__ __launch_bounds__(256)
void edge_scatter(const int* __restrict__ ei, int E,
                  int* __restrict__ cursor, int2* __restrict__ elist) {
    int e = blockIdx.x * blockDim.x + threadIdx.x;
    if (e >= E) return;
    int d = ei[E + e];
    int slot = atomicAdd(&cursor[d], 1);        // sentinel keeps non-bucketed negative
    if (slot >= 0) elist[slot] = make_int2(ei[e], d);
}

// ---------------- edge messages: dst-contiguous tiles, LDS segmented combine ----------------
template<int KHALF>
__global__ __launch_bounds__(256, 2)
void edge_msg_seg(int level, const int* __restrict__ etot,
                  const int2* __restrict__ elist, int ecap,
                  const __bf16* __restrict__ W1T, const __bf16* __restrict__ W2T,
                  const float* __restrict__ b1, const float* __restrict__ b2,
                  const __bf16* __restrict__ mir, float* __restrict__ agg) {
    const int gi = blockIdx.y;
    const int b = (level - 1) * 4 + gi;
    const int ecnt = etot[b];
    const int ntiles = (ecnt + 15) >> 4;
    if (ntiles == 0) return;

    __shared__ __bf16 st[16][264];
    __shared__ __bf16 hid[16][136];
    __shared__ float msgbuf[16][132];
    __shared__ int ssrc[16], sdst[16];
    __shared__ int leadrow[17];
    __shared__ int nlead;

    const int tid = threadIdx.x;
    const int lane = tid & 63;
    const int w = tid >> 6;
    const __bf16* w1 = W1T + (size_t)gi * 128 * 256;
    const __bf16* w2 = W2T + (size_t)gi * 128 * 128;

    bf16x8 w1f[KHALF][2], w2f[4][2];
    #pragma unroll
    for (int kk = 0; kk < KHALF; ++kk)
        #pragma unroll
        for (int j = 0; j < 2; ++j) {
            int col = w * 32 + j * 16 + (lane & 15);
            w1f[kk][j] = *(const bf16x8*)&w1[(size_t)col * 256 + kk * 32 + (lane >> 4) * 8];
        }
    #pragma unroll
    for (int kk = 0; kk < 4; ++kk)
        #pragma unroll
        for (int j = 0; j < 2; ++j) {
            int col = w * 32 + j * 16 + (lane & 15);
            w2f[kk][j] = *(const bf16x8*)&w2[(size_t)col * 128 + kk * 32 + (lane >> 4) * 8];
        }
    float b1c[2], b2c[2];
    #pragma unroll
    for (int j = 0; j < 2; ++j) {
        int col = w * 32 + j * 16 + (lane & 15);
        b1c[j] = b1[gi * H + col];
        b2c[j] = b2[gi * H + col];
    }

    for (int t = blockIdx.x; t < ntiles; t += gridDim.x) {
        const int base = t * 16;
        const int rem = min(16, ecnt - base);
        if (tid < 64) {
            if (tid < 16) {
                int2 e = elist[b * ecap + base + min(tid, rem - 1)];
                ssrc[tid] = e.x;
                sdst[tid] = e.y;
            }
            bool flag = (tid < rem) && (tid == 0 || sdst[tid] != sdst[tid - 1]);
            unsigned long long m = __ballot(flag);
            if (flag) {
                int rank = __popcll(m & ((1ull << tid) - 1));
                leadrow[rank] = tid;
            }
            if (tid == 0) {
                int nl = __popcll(m);
                nlead = nl;
                leadrow[nl] = rem;
            }
        }
        __syncthreads();
        #pragma unroll
        for (int rep = 0; rep < KHALF / 4; ++rep) {
            int idx = rep * 256 + tid;
            int r = idx / (KHALF * 4);
            int c = idx - r * (KHALF * 4);
            *(bf16x8*)&st[r][c * 8] = *(const bf16x8*)&mir[(size_t)ssrc[r] * 256 + c * 8];
        }
        __syncthreads();
        f32x4 acc[2] = {};
        #pragma unroll
        for (int kk = 0; kk < KHALF; ++kk) {
            bf16x8 a = *(const bf16x8*)&st[lane & 15][kk * 32 + (lane >> 4) * 8];
            #pragma unroll
            for (int j = 0; j < 2; ++j)
                acc[j] = __builtin_amdgcn_mfma_f32_16x16x32_bf16(a, w1f[kk][j], acc[j], 0, 0, 0);
        }
        #pragma unroll
        for (int j = 0; j < 2; ++j) {
            int col = w * 32 + j * 16 + (lane & 15);
            #pragma unroll
            for (int r = 0; r < 4; ++r)
                hid[(lane >> 4) * 4 + r][col] = (__bf16)fmaxf(acc[j][r] + b1c[j], 0.f);
        }
        __syncthreads();
        f32x4 acc2[2] = {};
        #pragma unroll
        for (int kk = 0; kk < 4; ++kk) {
            bf16x8 a = *(const bf16x8*)&hid[lane & 15][kk * 32 + (lane >> 4) * 8];
            #pragma unroll
            for (int j = 0; j < 2; ++j)
                acc2[j] = __builtin_amdgcn_mfma_f32_16x16x32_bf16(a, w2f[kk][j], acc2[j], 0, 0, 0);
        }
        #pragma unroll
        for (int j = 0; j < 2; ++j) {
            int col = w * 32 + j * 16 + (lane & 15);
            #pragma unroll
            for (int r = 0; r < 4; ++r)
                msgbuf[(lane >> 4) * 4 + r][col] = acc2[j][r] + b2c[j];
        }
        __syncthreads();
        const int nl = nlead;
        for (int idx = tid; idx < (nl << 7); idx += 256) {
            int li = idx >> 7, c = idx & 127;
            int r0 = leadrow[li], r1 = leadrow[li + 1];
            float s = msgbuf[r0][c];
            for (int r = r0 + 1; r < r1; ++r) s += msgbuf[r][c];
            atomicAdd(&agg[(size_t)sdst[r0] * H + c], s);
        }
        __syncthreads();
    }
}

// ---------------- GRU: h = (1-z)*tanh(inn + r*bhn), x = agg; writes out(f32) + mir(bf16) ----------------
__global__ __launch_bounds__(256, 2)
void gru_mfma(const int* __restrict__ ncnt, const int* __restrict__ nbuf, int ncap,
              int level, int N,
              const __bf16* __restrict__ WihT, const float* __restrict__ bih,
              const float* __restrict__ bhh,
              const float* __restrict__ agg, float* __restrict__ out,
              __bf16* __restrict__ mir) {
    const int gi = blockIdx.y;
    const int bucket = (level - 1) * 4 + gi;
    const int cnt = min(ncnt[bucket], ncap);
    const int ntiles = (cnt + 15) >> 4;
    if (ntiles == 0) return;

    __shared__ __bf16 x[16][136];
    __shared__ int nid[16];
    const int tid = threadIdx.x;
    const int lane = tid & 63;
    const int w = tid >> 6;
    const __bf16* wih = WihT + (size_t)gi * 384 * 128;

    bf16x8 wf[4][3][2];
    #pragma unroll
    for (int kk = 0; kk < 4; ++kk)
        #pragma unroll
        for (int p = 0; p < 3; ++p)
            #pragma unroll
            for (int j = 0; j < 2; ++j) {
                int oc = p * 128 + w * 32 + j * 16 + (lane & 15);
                wf[kk][p][j] = *(const bf16x8*)&wih[(size_t)oc * 128 + kk * 32 + (lane >> 4) * 8];
            }
    float bir[2], biz[2], bin[2], bhn[2];
    #pragma unroll
    for (int j = 0; j < 2; ++j) {
        int col = w * 32 + j * 16 + (lane & 15);
        bir[j] = bih[gi * 384 + col] + bhh[gi * 384 + col];
        biz[j] = bih[gi * 384 + 128 + col] + bhh[gi * 384 + 128 + col];
        bin[j] = bih[gi * 384 + 256 + col];
        bhn[j] = bhh[gi * 384 + 256 + col];
    }

    for (int t = blockIdx.x; t < ntiles; t += gridDim.x) {
        const int base = t * 16;
        const int rem = min(16, cnt - base);
        if (tid < 16) nid[tid] = nbuf[bucket * ncap + base + min(tid, rem - 1)];
        __syncthreads();
        #pragma unroll
        for (int rep = 0; rep < 2; ++rep) {
            int idx = rep * 256 + tid;
            int row = idx >> 5, c4 = idx & 31;
            f32x4 v = *(const f32x4*)&agg[(size_t)nid[row] * H + c4 * 4];
            bf16x4 p;
            p[0] = (__bf16)v[0]; p[1] = (__bf16)v[1]; p[2] = (__bf16)v[2]; p[3] = (__bf16)v[3];
            *(bf16x4*)&x[row][c4 * 4] = p;
        }
        __syncthreads();
        f32x4 acc[3][2] = {};
        #pragma unroll
        for (int kk = 0; kk < 4; ++kk) {
            bf16x8 a = *(const bf16x8*)&x[lane & 15][kk * 32 + (lane >> 4) * 8];
            #pragma unroll
            for (int p = 0; p < 3; ++p)
                #pragma unroll
                for (int j = 0; j < 2; ++j)
                    acc[p][j] = __builtin_amdgcn_mfma_f32_16x16x32_bf16(a, wf[kk][p][j], acc[p][j], 0, 0, 0);
        }
        #pragma unroll
        for (int j = 0; j < 2; ++j) {
            int col = w * 32 + j * 16 + (lane & 15);
            #pragma unroll
            for (int r = 0; r < 4; ++r) {
                int row = (lane >> 4) * 4 + r;
                if (row >= rem) continue;
                float rr = 1.f / (1.f + expf(-(acc[0][j][r] + bir[j])));
                float zz = 1.f / (1.f + expf(-(acc[1][j][r] + biz[j])));
                float nn = tanhf(acc[2][j][r] + bin[j] + rr * bhn[j]);
                float h = (1.f - zz) * nn;
                out[(size_t)N * H + (size_t)nid[row] * H + col] = h;
                mir[(size_t)nid[row] * 256 + 128 + col] = (__bf16)h;
            }
        }
        __syncthreads();
    }
}

extern "C" void kernel_launch(void* const* d_in, const int* in_sizes, int n_in,
                              void* d_out, int out_size, void* d_ws, size_t ws_size,
                              hipStream_t stream) {
    const int*   gate    = (const int*)d_in[0];
    const int*   ei      = (const int*)d_in[1];
    const int*   lvl     = (const int*)d_in[2];
    const float* Ws_self = (const float*)d_in[4];
    const float* Ws_nbr  = (const float*)d_in[5];
    const float* Wt_self = (const float*)d_in[6];
    const float* Wt_nbr  = (const float*)d_in[7];
    const float* hs_W    = (const float*)d_in[8];
    const float* hs_b    = (const float*)d_in[9];
    const float* aW1     = (const float*)d_in[10];
    const float* ab1     = (const float*)d_in[11];
    const float* aW2     = (const float*)d_in[12];
    const float* ab2     = (const float*)d_in[13];
    const float* gWih    = (const float*)d_in[14];
    const float* gbih    = (const float*)d_in[15];
    // d_in[16] = gru_Whh unused (h == 0 at each node's single update)
    const float* gbhh    = (const float*)d_in[17];

    const int N = in_sizes[0];
    const int E = in_sizes[1] / 2;
    const int ECAP = ((E / 4) + 15) & ~15;
    const int NCAP = ((N / 4) + 15) & ~15;

    char* wsb = (char*)d_ws;
    size_t off = 0;
    float* agg = (float*)(wsb + off);         off += (size_t)N * H * sizeof(float);
    const size_t zstart = off;                // agg zeroed per-row by encoder
    int* cnt_in = (int*)(wsb + off);          off += (size_t)N * 6 * sizeof(int);
    int* cnt_out = (int*)(wsb + off);         off += (size_t)N * 6 * sizeof(int);
    int* ncnt = (int*)(wsb + off);            off += 8 * sizeof(int);
    int* galloc = (int*)(wsb + off);          off += 8 * sizeof(int); off = (off + 63) & ~(size_t)63;
    const size_t zero_bytes = off - zstart;   // cnts + ncnt + galloc (~2.9MB), 16B-multiple
    int* cursor = (int*)(wsb + off);          off += (size_t)N * sizeof(int); off = (off + 7) & ~(size_t)7;
    int2* elist = (int2*)(wsb + off);         off += (size_t)8 * ECAP * sizeof(int2);
    int* nbuf   = (int*)(wsb + off);          off += (size_t)8 * NCAP * sizeof(int);
    __bf16* mir = (__bf16*)(wsb + off);       off += (size_t)N * 256 * sizeof(__bf16);
    __bf16* W1T = (__bf16*)(wsb + off);       off += (size_t)4 * 128 * 256 * 2;
    __bf16* W2T = (__bf16*)(wsb + off);       off += (size_t)4 * 128 * 128 * 2;
    __bf16* WihT = (__bf16*)(wsb + off);      off += (size_t)4 * 384 * 128 * 2;
    __bf16* hsWT = (__bf16*)(wsb + off);      off += (size_t)128 * 256 * 2;

    float* out = (float*)d_out;

    // planes 0..13: weight transposes; plane 14: zero cnt/counter region
    prep_weights<<<dim3(48, 1, 15), 256, 0, stream>>>(
        aW1, aW2, gWih, hs_W, W1T, W2T, WihT, hsWT,
        (f32x4*)(wsb + zstart), (int)(zero_bytes / 16));
    hist_kernel<<<(E + 255) / 256, 256, 0, stream>>>(gate, ei, E, cnt_in, cnt_out);
    // fused: blocks 0..63 node-alloc, blocks 64..511 encoder
    alloc_enc<<<512, 256, 0, stream>>>(
        gate, lvl, cnt_in, cnt_out, N, ECAP, NCAP, galloc, ncnt, cursor, nbuf,
        Ws_self, Ws_nbr, Wt_self, Wt_nbr, hsWT, hs_b, out, mir, agg, 64);
    edge_scatter<<<(E + 255) / 256, 256, 0, stream>>>(ei, E, cursor, elist);

    // level 1: hf == 0 everywhere -> KHALF=4 (only hs K-rows of W1)
    edge_msg_seg<4><<<dim3(128, 4), 256, 0, stream>>>(
        1, galloc, elist, ECAP, W1T, W2T, ab1, ab2, mir, agg);
    gru_mfma<<<dim3(128, 4), 256, 0, stream>>>(
        ncnt, nbuf, NCAP, 1, N, WihT, gbih, gbhh, agg, out, mir);
    edge_msg_seg<8><<<dim3(128, 4), 256, 0, stream>>>(
        2, galloc, elist, ECAP, W1T, W2T, ab1, ab2, mir, agg);
    gru_mfma<<<dim3(128, 4), 256, 0, stream>>>(
        ncnt, nbuf, NCAP, 2, N, WihT, gbih, gbhh, agg, out, mir);
}